// Round 9
// baseline (121.214 us; speedup 1.0000x reference)
//
#include <hip/hip_runtime.h>
#include <hip/hip_fp16.h>

typedef _Float16 f16x8 __attribute__((ext_vector_type(8)));
typedef _Float16 f16x4 __attribute__((ext_vector_type(4)));
typedef float f32x4 __attribute__((ext_vector_type(4)));

// Workspace layout (bytes):
//   qv     [0,       65536)   : 32x512 f32   q = query @ Wq^T
//   bfrag  [65536,   589824)  : 512x512 f16  Wk^T in MFMA-fragment-major layout
//   scores [589824,  851968)  : 32x2048 f32  pre-softmax scores
//   vpart  [851968,  1900544) : 1024x512 f16 per-(b,sc) normalized attn@keys
#define WS_QV 0
#define WS_BF 65536
#define WS_SC 589824
#define WS_VP 851968

#define GLOAD_LDS16(g, l)                                              \
  __builtin_amdgcn_global_load_lds(                                    \
      (const __attribute__((address_space(1))) void*)(g),              \
      (__attribute__((address_space(3))) void*)(l), 16, 0, 0)

// ---------------- P: qv = query@Wq^T (fp32) + prepack Wk -> fp16 fragment layout ----
__global__ __launch_bounds__(256) void prep_kernel(
    const float* __restrict__ query, const float* __restrict__ Wq,
    const float* __restrict__ Wk, float* __restrict__ qv,
    _Float16* __restrict__ bfrag) {
  const int blk = blockIdx.x, tid = threadIdx.x;
  if (blk < 64) {
    const int b = blk >> 1;
    const int h = ((blk & 1) << 8) + tid;
    const float4* qr = (const float4*)(query + (size_t)b * 512);
    const float4* wr = (const float4*)(Wq + (size_t)h * 512);
    float acc = 0.f;
#pragma unroll 8
    for (int i = 0; i < 128; ++i) {
      float4 a = qr[i], w = wr[i];
      acc += a.x * w.x + a.y * w.y + a.z * w.z + a.w * w.w;
    }
    qv[b * 512 + h] = acc;
  } else {
    // B-fragment for mfma_f32_16x16x32_f16: unit u = nt*16 + ks
    // lane l supplies B[k = 32*ks + 8*(l>>4)+e][col = 16*nt + (l&15)] = Wk[col][k]
    const int u = (blk - 64) * 4 + (tid >> 6);
    const int l = tid & 63;
    const int col = ((u >> 4) << 4) + (l & 15);
    const int k0 = ((u & 15) << 5) + ((l >> 4) << 3);
    const float4* src = (const float4*)(Wk + (size_t)col * 512 + k0);
    float4 x = src[0], y = src[1];
    f16x8 v;
    v[0] = (_Float16)x.x; v[1] = (_Float16)x.y;
    v[2] = (_Float16)x.z; v[3] = (_Float16)x.w;
    v[4] = (_Float16)y.x; v[5] = (_Float16)y.y;
    v[6] = (_Float16)y.z; v[7] = (_Float16)y.w;
    *(f16x8*)(bfrag + (size_t)u * 512 + l * 8) = v;
  }
}

// ---------------- G: scores GEMM with counted-vmcnt pipeline (T3+T4) ---------------
// Grid 1024 row-tiles of 64; 1024 thr / 16 waves; wave (wm,wn) = 32 rows x 64 h.
// BK=32, 4-buffer LDS ring (4 x 8KB fp32), glds staging, prefetch depth 3.
// Raw s_barrier (no vmcnt drain) + literal s_waitcnt vmcnt(2): stage loads for
// tiles kt+1,kt+2 stay in flight across the barrier; bf loads self-drain via
// their consuming MFMAs, so the count is exact.
__global__ __launch_bounds__(1024) void gemm_kernel(
    const float* __restrict__ keys, const _Float16* __restrict__ bfrag,
    const float* __restrict__ qv, const float* __restrict__ w_att,
    float* __restrict__ scores) {
  __shared__ __align__(128) unsigned char lds[32768];   // 4 x (64 rows x 32 k fp32)
  __shared__ float sred[512];                           // 16 waves x 32 rows
  const int tid = threadIdx.x, w = tid >> 6, l = tid & 63;
  const int row0 = blockIdx.x * 64;
  const int b = row0 >> 11;
  const int wm = w >> 3, wn = w & 7;

  // staging (tid<512): row sr = tid>>3, 16B slot ss = tid&7; source pre-swizzled
  // (slot ^ (row&7)) so the linear glds dest equals the swizzled layout.
  const int sr = tid >> 3, ss = tid & 7;
  const char* gsrc = (const char*)keys + (size_t)(row0 + sr) * 2048 +
                     ((ss ^ (sr & 7)) << 4);

  auto STAGE = [&](int kt) {
    if (tid < 512)
      GLOAD_LDS16(gsrc + (size_t)kt * 128, lds + ((kt & 3) << 13) + tid * 16);
  };

  f32x4 acc[2][4] = {};
  const int arow0 = wm * 32 + (l & 15);
  const int aka = (l >> 4) << 5;

  auto COMPUTE = [&](int kt) {
    const unsigned char* buf = lds + ((kt & 3) << 13);
    f16x8 af[2];
#pragma unroll
    for (int mt = 0; mt < 2; ++mt) {
      const int rr = arow0 + mt * 16;
      const int cb = aka ^ ((rr & 7) << 4);
      const float4 x = *(const float4*)(buf + rr * 128 + cb);
      const float4 y = *(const float4*)(buf + rr * 128 + (cb ^ 16));
      f16x8 h;
      h[0] = (_Float16)x.x; h[1] = (_Float16)x.y;
      h[2] = (_Float16)x.z; h[3] = (_Float16)x.w;
      h[4] = (_Float16)y.x; h[5] = (_Float16)y.y;
      h[6] = (_Float16)y.z; h[7] = (_Float16)y.w;
      af[mt] = h;
    }
    f16x8 bf[4];
#pragma unroll
    for (int nt = 0; nt < 4; ++nt) {
      const int u = ((wn << 2) + nt) * 16 + kt;
      bf[nt] = *(const f16x8*)(bfrag + (size_t)u * 512 + l * 8);
    }
#pragma unroll
    for (int mt = 0; mt < 2; ++mt)
#pragma unroll
      for (int nt = 0; nt < 4; ++nt)
        acc[mt][nt] = __builtin_amdgcn_mfma_f32_16x16x32_f16(
            af[mt], bf[nt], acc[mt][nt], 0, 0, 0);
  };

  STAGE(0); STAGE(1); STAGE(2);

#define GI(KT, VM)                                                     \
  asm volatile("s_waitcnt vmcnt(" #VM ")" ::: "memory");               \
  asm volatile("s_barrier" ::: "memory");                              \
  if ((KT) < 13) STAGE((KT) + 3);                                      \
  COMPUTE(KT);

  GI(0, 2)  GI(1, 2)  GI(2, 2)  GI(3, 2)
  GI(4, 2)  GI(5, 2)  GI(6, 2)  GI(7, 2)
  GI(8, 2)  GI(9, 2)  GI(10, 2) GI(11, 2)
  GI(12, 2) GI(13, 2) GI(14, 1) GI(15, 0)
#undef GI

  // ---- epilogue: tanh(qv + k) * w_att, partial over this wave's 64 h
  float rs[8];
#pragma unroll
  for (int i = 0; i < 8; ++i) rs[i] = 0.f;
#pragma unroll
  for (int nt = 0; nt < 4; ++nt) {
    const int h = (wn << 6) + (nt << 4) + (l & 15);
    const float q = qv[b * 512 + h];
    const float wa = w_att[h];
#pragma unroll
    for (int mt = 0; mt < 2; ++mt)
#pragma unroll
      for (int r = 0; r < 4; ++r) {
        float x = q + acc[mt][nt][r];
        float e = __expf(x + x);
        float t = 1.f - __fdividef(2.f, e + 1.f);
        rs[mt * 4 + r] = __builtin_fmaf(t, wa, rs[mt * 4 + r]);
      }
  }
#pragma unroll
  for (int st = 1; st <= 8; st <<= 1)
#pragma unroll
    for (int i = 0; i < 8; ++i)
      rs[i] += __shfl_xor(rs[i], st, 64);

  {
    const int idx = l & 15;
    if (idx < 8) {
      float v = rs[0];
#pragma unroll
      for (int i = 1; i < 8; ++i) v = (idx == i) ? rs[i] : v;
      // local row: mt*16 + (l>>4)*4 + r
      const int rloc = ((idx >> 2) << 4) + ((l >> 4) << 2) + (idx & 3);
      sred[w * 32 + rloc] = v;
    }
  }
  __syncthreads();
  if (tid < 64) {
    const int wmq = tid >> 5, rl = tid & 31;
    float s = 0.f;
#pragma unroll
    for (int wn2 = 0; wn2 < 8; ++wn2)
      s += sred[(((wmq << 3) + wn2) << 5) + rl];
    scores[row0 + (wmq << 5) + rl] = s;
  }
}

// ---------------- S: global softmax + attn + normalized V-partial ------------------
// Grid 1024 = (b, sc): softmax over full row, V over 64-row chunk.
__global__ __launch_bounds__(256) void softv_kernel(
    const float* __restrict__ keys, const float* __restrict__ scores,
    float* __restrict__ attn, _Float16* __restrict__ vpart) {
  __shared__ float pe[2048];
  __shared__ float red_mx[4], red_se[4];
  __shared__ float4 comb[128];
  const int tid = threadIdx.x;
  const int b = blockIdx.x >> 5, sc = blockIdx.x & 31;
  const float* srow = scores + (size_t)b * 2048;

  float sv[8];
  float mx = -1e30f;
#pragma unroll
  for (int i = 0; i < 8; ++i) {
    sv[i] = srow[i * 256 + tid];
    mx = fmaxf(mx, sv[i]);
  }
#pragma unroll
  for (int st = 32; st >= 1; st >>= 1) mx = fmaxf(mx, __shfl_xor(mx, st, 64));
  if ((tid & 63) == 0) red_mx[tid >> 6] = mx;
  __syncthreads();
  mx = fmaxf(fmaxf(red_mx[0], red_mx[1]), fmaxf(red_mx[2], red_mx[3]));

  float se = 0.f;
#pragma unroll
  for (int i = 0; i < 8; ++i) {
    float e = __expf(sv[i] - mx);
    pe[i * 256 + tid] = e;
    se += e;
  }
#pragma unroll
  for (int st = 32; st >= 1; st >>= 1) se += __shfl_xor(se, st, 64);
  if ((tid & 63) == 0) red_se[tid >> 6] = se;
  __syncthreads();     // pe[] complete + red_se visible
  se = red_se[0] + red_se[1] + red_se[2] + red_se[3];
  const float rinv = 1.f / se;

  if (tid < 64) {
    int s = sc * 64 + tid;
    attn[(size_t)b * 2048 + s] = pe[s] * rinv;
  }

  // V: thread (c4, rg): float4 col c4, rows rg*32..+32 of this chunk
  const int c4 = tid & 127, rg = tid >> 7;
  const float4* kb = (const float4*)(keys + ((size_t)(b * 2048 + sc * 64 + rg * 32)) * 512);
  float4 a; a.x = 0.f; a.y = 0.f; a.z = 0.f; a.w = 0.f;
#pragma unroll 4
  for (int i = 0; i < 32; ++i) {
    float p = pe[sc * 64 + rg * 32 + i];
    float4 kv = kb[(size_t)i * 128 + c4];
    a.x = __builtin_fmaf(p, kv.x, a.x);
    a.y = __builtin_fmaf(p, kv.y, a.y);
    a.z = __builtin_fmaf(p, kv.z, a.z);
    a.w = __builtin_fmaf(p, kv.w, a.w);
  }
  if (rg) comb[c4] = a;
  __syncthreads();
  if (!rg) {
    float4 o = comb[c4];
    f16x4 h;
    h[0] = (_Float16)((a.x + o.x) * rinv);
    h[1] = (_Float16)((a.y + o.y) * rinv);
    h[2] = (_Float16)((a.z + o.z) * rinv);
    h[3] = (_Float16)((a.w + o.w) * rinv);
    *(f16x4*)(vpart + (size_t)blockIdx.x * 512 + c4 * 4) = h;
  }
}

// ---------------- R: reduce 32 chunk-partials -> out -------------------------------
__global__ __launch_bounds__(256) void reduce_kernel(
    const _Float16* __restrict__ vpart, float* __restrict__ out) {
  const int t = blockIdx.x * 256 + threadIdx.x;   // 16384 outputs
  const int b = t >> 9, d = t & 511;
  float s = 0.f;
#pragma unroll
  for (int sc = 0; sc < 32; ++sc)
    s += (float)vpart[((size_t)(b * 32 + sc)) * 512 + d];
  out[t] = s;
}

extern "C" void kernel_launch(void* const* d_in, const int* in_sizes, int n_in,
                              void* d_out, int out_size, void* d_ws, size_t ws_size,
                              hipStream_t stream) {
  const float* query = (const float*)d_in[0];
  const float* keys  = (const float*)d_in[1];
  const float* Wq    = (const float*)d_in[2];
  const float* Wk    = (const float*)d_in[3];
  const float* w_att = (const float*)d_in[4];
  float* out  = (float*)d_out;                  // [32,512]
  float* attn = out + 16384;                    // [32,2048]
  char* ws = (char*)d_ws;
  float*    qv     = (float*)(ws + WS_QV);
  _Float16* bfrag  = (_Float16*)(ws + WS_BF);
  float*    scores = (float*)(ws + WS_SC);
  _Float16* vpart  = (_Float16*)(ws + WS_VP);

  prep_kernel<<<192, 256, 0, stream>>>(query, Wq, Wk, qv, bfrag);
  gemm_kernel<<<1024, 1024, 0, stream>>>(keys, bfrag, qv, w_att, scores);
  softv_kernel<<<1024, 256, 0, stream>>>(keys, scores, attn, vpart);
  reduce_kernel<<<64, 256, 0, stream>>>(vpart, out);
}

// Round 10
// 111.738 us; speedup vs baseline: 1.0848x; 1.0848x over previous
//
#include <hip/hip_runtime.h>
#include <hip/hip_fp16.h>

typedef _Float16 f16x8 __attribute__((ext_vector_type(8)));
typedef _Float16 f16x4 __attribute__((ext_vector_type(4)));
typedef float f32x4 __attribute__((ext_vector_type(4)));

// Workspace layout (bytes):
//   qv     [0,       65536)   : 32x512 f32   q = query @ Wq^T
//   bfrag  [65536,   589824)  : 512x512 f16  Wk^T in MFMA-fragment-major layout
//   scores [589824,  851968)  : 32x2048 f32  pre-softmax scores
//   vpart  [851968,  1900544) : 1024x512 f16 per-(b,sc) normalized attn@keys
#define WS_QV 0
#define WS_BF 65536
#define WS_SC 589824
#define WS_VP 851968

#define GLOAD_LDS16(g, l)                                              \
  __builtin_amdgcn_global_load_lds(                                    \
      (const __attribute__((address_space(1))) void*)(g),              \
      (__attribute__((address_space(3))) void*)(l), 16, 0, 0)

// ---------------- P: qv = query@Wq^T (fp32) + prepack Wk -> fp16 fragment layout ----
__global__ __launch_bounds__(256) void prep_kernel(
    const float* __restrict__ query, const float* __restrict__ Wq,
    const float* __restrict__ Wk, float* __restrict__ qv,
    _Float16* __restrict__ bfrag) {
  const int blk = blockIdx.x, tid = threadIdx.x;
  if (blk < 64) {
    const int b = blk >> 1;
    const int h = ((blk & 1) << 8) + tid;
    const float4* qr = (const float4*)(query + (size_t)b * 512);
    const float4* wr = (const float4*)(Wq + (size_t)h * 512);
    float acc = 0.f;
#pragma unroll 8
    for (int i = 0; i < 128; ++i) {
      float4 a = qr[i], w = wr[i];
      acc += a.x * w.x + a.y * w.y + a.z * w.z + a.w * w.w;
    }
    qv[b * 512 + h] = acc;
  } else {
    // B-fragment for mfma_f32_16x16x32_f16: unit u = nt*16 + ks
    // lane l supplies B[k = 32*ks + 8*(l>>4)+e][col = 16*nt + (l&15)] = Wk[col][k]
    const int u = (blk - 64) * 4 + (tid >> 6);
    const int l = tid & 63;
    const int col = ((u >> 4) << 4) + (l & 15);
    const int k0 = ((u & 15) << 5) + ((l >> 4) << 3);
    const float4* src = (const float4*)(Wk + (size_t)col * 512 + k0);
    float4 x = src[0], y = src[1];
    f16x8 v;
    v[0] = (_Float16)x.x; v[1] = (_Float16)x.y;
    v[2] = (_Float16)x.z; v[3] = (_Float16)x.w;
    v[4] = (_Float16)y.x; v[5] = (_Float16)y.y;
    v[6] = (_Float16)y.z; v[7] = (_Float16)y.w;
    *(f16x8*)(bfrag + (size_t)u * 512 + l * 8) = v;
  }
}

// ---------------- G: scores GEMM with bf register-prefetch pipeline ----------------
// Grid 1024 row-tiles of 64; 1024 thr / 16 waves; wave (wm,wn) = 32 rows x 64 h.
// BK=64 per barrier-iteration (8 iters), A staged fp32 via glds into 3x16KB ring,
// bf (Wk frags) double-set register prefetch issued one half-step ahead of use.
// Raw s_barrier (no drain); compiler-inserted vmcnts are FIFO-exact: waiting a bf
// set never forces the younger in-flight stage/bf (verified issue-order analysis).
__global__ __launch_bounds__(1024) void gemm_kernel(
    const float* __restrict__ keys, const _Float16* __restrict__ bfrag,
    const float* __restrict__ qv, const float* __restrict__ w_att,
    float* __restrict__ scores) {
  __shared__ __align__(128) unsigned char ring[49152];  // 3 x (64 rows x 256B fp32)
  __shared__ float sred[512];                           // 16 waves x 32 rows
  const int tid = threadIdx.x, w = tid >> 6, l = tid & 63;
  const int row0 = blockIdx.x * 64;
  const int b = row0 >> 11;
  const int wm = w >> 3, wn = w & 7;

  // staging: thread -> row sr (0..63), 16B slot ss (0..15); source pre-swizzled
  // (slot ^ (row&7)) so the linear glds dest realizes the swizzled layout.
  const int sr = tid >> 4, ss = tid & 15;
  const char* gsrc = (const char*)keys + (size_t)(row0 + sr) * 2048 +
                     ((ss ^ (sr & 7)) << 4);

  auto STAGE = [&](int kt) {
    GLOAD_LDS16(gsrc + (size_t)kt * 256, ring + (kt % 3) * 16384 + tid * 16);
  };

  f32x4 acc[2][4] = {};
  f16x8 bfA[4], bfB[4];
  const int arow0 = wm * 32 + (l & 15);
  const int aka = (l >> 4) << 5;

  auto BFLOAD = [&](f16x8* dst, int KS) {
#pragma unroll
    for (int nt = 0; nt < 4; ++nt) {
      const int u = ((wn << 2) + nt) * 16 + KS;
      dst[nt] = *(const f16x8*)(bfrag + (size_t)u * 512 + l * 8);
    }
  };
  auto AFLOAD = [&](int kt, int ks, f16x8* af) {
    const unsigned char* buf = ring + (kt % 3) * 16384;
#pragma unroll
    for (int mt = 0; mt < 2; ++mt) {
      const int rr = arow0 + mt * 16;
      const int cb = (ks * 128 + aka) ^ ((rr & 7) << 4);
      const float4 x = *(const float4*)(buf + rr * 256 + cb);
      const float4 y = *(const float4*)(buf + rr * 256 + (cb ^ 16));
      f16x8 h;
      h[0] = (_Float16)x.x; h[1] = (_Float16)x.y;
      h[2] = (_Float16)x.z; h[3] = (_Float16)x.w;
      h[4] = (_Float16)y.x; h[5] = (_Float16)y.y;
      h[6] = (_Float16)y.z; h[7] = (_Float16)y.w;
      af[mt] = h;
    }
  };
  auto MM = [&](f16x8* af, f16x8* bf) {
    __builtin_amdgcn_s_setprio(1);
#pragma unroll
    for (int mt = 0; mt < 2; ++mt)
#pragma unroll
      for (int nt = 0; nt < 4; ++nt)
        acc[mt][nt] = __builtin_amdgcn_mfma_f32_16x16x32_f16(
            af[mt], bf[nt], acc[mt][nt], 0, 0, 0);
    __builtin_amdgcn_s_setprio(0);
  };

  // ---- prologue: stage A(0),A(1); prefetch bfA=(0,0); wait A(0) only
  STAGE(0);
  STAGE(1);
  __builtin_amdgcn_sched_barrier(0);
  BFLOAD(bfA, 0);
  __builtin_amdgcn_sched_barrier(0);
  asm volatile("s_waitcnt vmcnt(5)" ::: "memory");   // leave stage(1)+bfA in flight
  __builtin_amdgcn_s_barrier();

#pragma unroll
  for (int kt = 0; kt < 8; ++kt) {
    // ks=0: prefetch bfB=(kt,1); compute with bfA=(kt,0)
    BFLOAD(bfB, kt * 2 + 1);
    __builtin_amdgcn_sched_barrier(0);
    {
      f16x8 af[2];
      AFLOAD(kt, 0, af);
      MM(af, bfA);
    }
    // ks=1: prefetch bfA=(kt+1,0); compute with bfB
    if (kt < 7) BFLOAD(bfA, (kt + 1) * 2);
    __builtin_amdgcn_sched_barrier(0);
    {
      f16x8 af[2];
      AFLOAD(kt, 1, af);
      MM(af, bfB);
    }
    __builtin_amdgcn_sched_barrier(0);
    if (kt < 6) STAGE(kt + 2);
    if (kt < 7) __builtin_amdgcn_s_barrier();
  }

  // ---- epilogue: tanh(qv + k) * w_att, partial over this wave's 64 h
  float rs[8];
#pragma unroll
  for (int i = 0; i < 8; ++i) rs[i] = 0.f;
#pragma unroll
  for (int nt = 0; nt < 4; ++nt) {
    const int h = (wn << 6) + (nt << 4) + (l & 15);
    const float q = qv[b * 512 + h];
    const float wa = w_att[h];
#pragma unroll
    for (int mt = 0; mt < 2; ++mt)
#pragma unroll
      for (int r = 0; r < 4; ++r) {
        float x = q + acc[mt][nt][r];
        float e = __expf(x + x);
        float t = 1.f - __fdividef(2.f, e + 1.f);
        rs[mt * 4 + r] = __builtin_fmaf(t, wa, rs[mt * 4 + r]);
      }
  }
#pragma unroll
  for (int st = 1; st <= 8; st <<= 1)
#pragma unroll
    for (int i = 0; i < 8; ++i)
      rs[i] += __shfl_xor(rs[i], st, 64);

  __syncthreads();
  {
    const int idx = l & 15;
    if (idx < 8) {
      float v = rs[0];
#pragma unroll
      for (int i = 1; i < 8; ++i) v = (idx == i) ? rs[i] : v;
      // local row: mt*16 + (l>>4)*4 + r
      const int rloc = ((idx >> 2) << 4) + ((l >> 4) << 2) + (idx & 3);
      sred[w * 32 + rloc] = v;
    }
  }
  __syncthreads();
  if (tid < 64) {
    const int wmq = tid >> 5, rl = tid & 31;
    float s = 0.f;
#pragma unroll
    for (int wn2 = 0; wn2 < 8; ++wn2)
      s += sred[(((wmq << 3) + wn2) << 5) + rl];
    scores[row0 + (wmq << 5) + rl] = s;
  }
}

// ---------------- S: global softmax + attn + normalized V-partial ------------------
// Grid 1024 = (b, sc): softmax over full row, V over 64-row chunk.
__global__ __launch_bounds__(256) void softv_kernel(
    const float* __restrict__ keys, const float* __restrict__ scores,
    float* __restrict__ attn, _Float16* __restrict__ vpart) {
  __shared__ float pe[2048];
  __shared__ float red_mx[4], red_se[4];
  __shared__ float4 comb[128];
  const int tid = threadIdx.x;
  const int b = blockIdx.x >> 5, sc = blockIdx.x & 31;
  const float* srow = scores + (size_t)b * 2048;

  float sv[8];
  float mx = -1e30f;
#pragma unroll
  for (int i = 0; i < 8; ++i) {
    sv[i] = srow[i * 256 + tid];
    mx = fmaxf(mx, sv[i]);
  }
#pragma unroll
  for (int st = 32; st >= 1; st >>= 1) mx = fmaxf(mx, __shfl_xor(mx, st, 64));
  if ((tid & 63) == 0) red_mx[tid >> 6] = mx;
  __syncthreads();
  mx = fmaxf(fmaxf(red_mx[0], red_mx[1]), fmaxf(red_mx[2], red_mx[3]));

  float se = 0.f;
#pragma unroll
  for (int i = 0; i < 8; ++i) {
    float e = __expf(sv[i] - mx);
    pe[i * 256 + tid] = e;
    se += e;
  }
#pragma unroll
  for (int st = 32; st >= 1; st >>= 1) se += __shfl_xor(se, st, 64);
  if ((tid & 63) == 0) red_se[tid >> 6] = se;
  __syncthreads();     // pe[] complete + red_se visible
  se = red_se[0] + red_se[1] + red_se[2] + red_se[3];
  const float rinv = 1.f / se;

  if (tid < 64) {
    int s = sc * 64 + tid;
    attn[(size_t)b * 2048 + s] = pe[s] * rinv;
  }

  // V: thread (c4, rg): float4 col c4, rows rg*32..+32 of this chunk
  const int c4 = tid & 127, rg = tid >> 7;
  const float4* kb = (const float4*)(keys + ((size_t)(b * 2048 + sc * 64 + rg * 32)) * 512);
  float4 a; a.x = 0.f; a.y = 0.f; a.z = 0.f; a.w = 0.f;
#pragma unroll 4
  for (int i = 0; i < 32; ++i) {
    float p = pe[sc * 64 + rg * 32 + i];
    float4 kv = kb[(size_t)i * 128 + c4];
    a.x = __builtin_fmaf(p, kv.x, a.x);
    a.y = __builtin_fmaf(p, kv.y, a.y);
    a.z = __builtin_fmaf(p, kv.z, a.z);
    a.w = __builtin_fmaf(p, kv.w, a.w);
  }
  if (rg) comb[c4] = a;
  __syncthreads();
  if (!rg) {
    float4 o = comb[c4];
    f16x4 h;
    h[0] = (_Float16)((a.x + o.x) * rinv);
    h[1] = (_Float16)((a.y + o.y) * rinv);
    h[2] = (_Float16)((a.z + o.z) * rinv);
    h[3] = (_Float16)((a.w + o.w) * rinv);
    *(f16x4*)(vpart + (size_t)blockIdx.x * 512 + c4 * 4) = h;
  }
}

// ---------------- R: reduce 32 chunk-partials -> out -------------------------------
__global__ __launch_bounds__(256) void reduce_kernel(
    const _Float16* __restrict__ vpart, float* __restrict__ out) {
  const int t = blockIdx.x * 256 + threadIdx.x;   // 16384 outputs
  const int b = t >> 9, d = t & 511;
  float s = 0.f;
#pragma unroll
  for (int sc = 0; sc < 32; ++sc)
    s += (float)vpart[((size_t)(b * 32 + sc)) * 512 + d];
  out[t] = s;
}

extern "C" void kernel_launch(void* const* d_in, const int* in_sizes, int n_in,
                              void* d_out, int out_size, void* d_ws, size_t ws_size,
                              hipStream_t stream) {
  const float* query = (const float*)d_in[0];
  const float* keys  = (const float*)d_in[1];
  const float* Wq    = (const float*)d_in[2];
  const float* Wk    = (const float*)d_in[3];
  const float* w_att = (const float*)d_in[4];
  float* out  = (float*)d_out;                  // [32,512]
  float* attn = out + 16384;                    // [32,2048]
  char* ws = (char*)d_ws;
  float*    qv     = (float*)(ws + WS_QV);
  _Float16* bfrag  = (_Float16*)(ws + WS_BF);
  float*    scores = (float*)(ws + WS_SC);
  _Float16* vpart  = (_Float16*)(ws + WS_VP);

  prep_kernel<<<192, 256, 0, stream>>>(query, Wq, Wk, qv, bfrag);
  gemm_kernel<<<1024, 1024, 0, stream>>>(keys, bfrag, qv, w_att, scores);
  softv_kernel<<<1024, 256, 0, stream>>>(keys, scores, attn, vpart);
  reduce_kernel<<<64, 256, 0, stream>>>(vpart, out);
}